// Round 1
// baseline (447.089 us; speedup 1.0000x reference)
//
#include <hip/hip_runtime.h>
#include <hip/hip_bf16.h>

typedef unsigned short u16;
typedef short short8 __attribute__((ext_vector_type(8)));
typedef float f32x4 __attribute__((ext_vector_type(4)));

#define OUTD 7
#define NROI 1024
#define CH 256
#define HH 256
#define WW 256
#define KDIM 12544   // 256*49
#define NHID 1024
#define KSPLIT 8

// ---------------- features (B,C,H,W) fp32 -> featT (B,H,W,C) bf16 ----------------
__global__ __launch_bounds__(256) void transpose_feat(const float* __restrict__ f,
                                                      __hip_bfloat16* __restrict__ ft) {
    __shared__ float tile[32][33];
    int pb = blockIdx.x;          // 0..2047 over p = y*256+x
    int cb = blockIdx.y;          // 0..7
    int b  = blockIdx.z;          // 0..1
    int tx = threadIdx.x & 31;
    int ty = threadIdx.x >> 5;    // 0..7
    const float* src = f + ((size_t)(b * CH + cb * 32)) * 65536 + (size_t)pb * 32;
#pragma unroll
    for (int i = 0; i < 4; ++i) {
        int c = ty + i * 8;
        tile[c][tx] = src[(size_t)c * 65536 + tx];
    }
    __syncthreads();
    __hip_bfloat16* dst = ft + ((size_t)b * 65536 + (size_t)pb * 32) * CH + cb * 32;
#pragma unroll
    for (int i = 0; i < 4; ++i) {
        int p = ty + i * 8;
        dst[(size_t)p * CH + tx] = __float2bfloat16(tile[tx][p]);
    }
}

// ---------------- w1 (K,N) fp32 -> w1t (N,K) bf16 ----------------
__global__ __launch_bounds__(256) void transpose_w1(const float* __restrict__ w1,
                                                    __hip_bfloat16* __restrict__ w1t) {
    __shared__ float tile[32][33];
    int kb = blockIdx.x;          // 0..391
    int nb = blockIdx.y;          // 0..31
    int tx = threadIdx.x & 31;
    int ty = threadIdx.x >> 5;
#pragma unroll
    for (int i = 0; i < 4; ++i) {
        int k = ty + i * 8;
        tile[k][tx] = w1[(size_t)(kb * 32 + k) * NHID + nb * 32 + tx];
    }
    __syncthreads();
#pragma unroll
    for (int i = 0; i < 4; ++i) {
        int nn = ty + i * 8;
        w1t[(size_t)(nb * 32 + nn) * KDIM + kb * 32 + tx] = __float2bfloat16(tile[tx][nn]);
    }
}

// ---------------- rotated RoI align: featT -> x (fp32, into d_out) + flat (bf16) ----------------
__global__ __launch_bounds__(256) void roi_align(const __hip_bfloat16* __restrict__ ft,
                                                 const float* __restrict__ rois,
                                                 float* __restrict__ x,
                                                 __hip_bfloat16* __restrict__ flat) {
    __shared__ float sbuf[KDIM];   // [c][bin], 50176 B
    int i = blockIdx.x;
    int c = threadIdx.x;
    float r0 = rois[i * 6 + 0], r1 = rois[i * 6 + 1], r2 = rois[i * 6 + 2];
    float r3 = rois[i * 6 + 3], r4 = rois[i * 6 + 4], th = rois[i * 6 + 5];
    int b = (int)r0;
    float cx = r1 * 0.125f, cy = r2 * 0.125f;
    float rw = fmaxf(r3 * 0.125f, 1.0f), rh = fmaxf(r4 * 0.125f, 1.0f);
    float bw = rw * (1.0f / 7.0f), bh = rh * (1.0f / 7.0f);
    float ct = cosf(th), st = sinf(th);
    const __hip_bfloat16* fb = ft + (size_t)b * 65536 * CH;

    for (int bin = 0; bin < 49; ++bin) {
        int ph = bin / 7, pw = bin - (bin / 7) * 7;
        float acc = 0.f;
#pragma unroll
        for (int s = 0; s < 4; ++s) {
            int sy = s >> 1, sx2 = s & 1;
            float yy = -rh * 0.5f + ((float)ph + ((float)sy + 0.5f) * 0.5f) * bh;
            float xx = -rw * 0.5f + ((float)pw + ((float)sx2 + 0.5f) * 0.5f) * bw;
            float xs = xx * ct - yy * st + cx;
            float ys = xx * st + yy * ct + cy;
            bool valid = (ys > -1.0f) && (ys < 256.0f) && (xs > -1.0f) && (xs < 256.0f);
            float ysc = fminf(fmaxf(ys, 0.f), 255.f);
            float xsc = fminf(fmaxf(xs, 0.f), 255.f);
            int yl = (int)floorf(ysc), xl = (int)floorf(xsc);
            int yh = min(yl + 1, 255), xh = min(xl + 1, 255);
            float ly = ysc - (float)yl, lx = xsc - (float)xl;
            float hy = 1.f - ly, hx = 1.f - lx;
            const __hip_bfloat16* p11 = fb + ((size_t)(yl * 256 + xl) << 8);
            const __hip_bfloat16* p12 = fb + ((size_t)(yl * 256 + xh) << 8);
            const __hip_bfloat16* p21 = fb + ((size_t)(yh * 256 + xl) << 8);
            const __hip_bfloat16* p22 = fb + ((size_t)(yh * 256 + xh) << 8);
            float v = hy * hx * __bfloat162float(p11[c]) + hy * lx * __bfloat162float(p12[c])
                    + ly * hx * __bfloat162float(p21[c]) + ly * lx * __bfloat162float(p22[c]);
            acc += valid ? v : 0.f;
        }
        sbuf[c * 49 + bin] = acc * 0.25f;
    }
    __syncthreads();
    size_t base = (size_t)i * KDIM;
    for (int j = threadIdx.x; j < KDIM; j += 256) {
        float v = sbuf[j];
        x[base + j] = v;
        flat[base + j] = __float2bfloat16(v);
    }
}

// ---------------- GEMM1: flat[1024,12544]bf16 @ w1t[1024,12544]^T -> part[ks][1024][1024] fp32 ----------------
// 128x128 tile, BK=64, 4 waves (2x2), 16x16x32 MFMA, XOR-8 quad swizzle in LDS.
__global__ __launch_bounds__(256) void gemm1(const u16* __restrict__ A,   // [1024][12544]
                                             const u16* __restrict__ Bt,  // [1024][12544]
                                             float* __restrict__ part) {
    const int K = KDIM;
    int nb = blockIdx.x, mb = blockIdx.y, ks = blockIdx.z;
    int steps = 24 + (ks < 4 ? 1 : 0);
    int kbase = (ks * 24 + (ks < 4 ? ks : 4)) * 64;
    __shared__ u16 As[128 * 64];
    __shared__ u16 Bs[128 * 64];
    int tid = threadIdx.x;
    int lane = tid & 63, w = tid >> 6;
    int wm = w >> 1, wn = w & 1;
    f32x4 acc[4][4] = {};
    const u16* Ab = A + (size_t)(mb * 128) * K;
    const u16* Bb = Bt + (size_t)(nb * 128) * K;

    for (int s = 0; s < steps; ++s) {
        int kk = kbase + s * 64;
        __syncthreads();
#pragma unroll
        for (int j = 0; j < 4; ++j) {
            int cid = tid + 256 * j;        // 0..1023 16B-chunks
            int row = cid >> 3, pq = cid & 7;
            int q = pq ^ (row & 7);         // logical quad stored at physical pq
            uint4 va = *(const uint4*)(Ab + (size_t)row * K + kk + q * 8);
            *(uint4*)(As + row * 64 + pq * 8) = va;
            uint4 vb = *(const uint4*)(Bb + (size_t)row * K + kk + q * 8);
            *(uint4*)(Bs + row * 64 + pq * 8) = vb;
        }
        __syncthreads();
#pragma unroll
        for (int kh = 0; kh < 2; ++kh) {
            short8 af[4], bf[4];
#pragma unroll
            for (int t = 0; t < 4; ++t) {
                int q = kh * 4 + (lane >> 4);
                int r = wm * 64 + t * 16 + (lane & 15);
                int pq = q ^ (r & 7);
                af[t] = *(const short8*)(As + r * 64 + pq * 8);
                int rb = wn * 64 + t * 16 + (lane & 15);
                int pqb = q ^ (rb & 7);
                bf[t] = *(const short8*)(Bs + rb * 64 + pqb * 8);
            }
#pragma unroll
            for (int mt = 0; mt < 4; ++mt)
#pragma unroll
                for (int nt = 0; nt < 4; ++nt)
                    acc[mt][nt] = __builtin_amdgcn_mfma_f32_16x16x32_bf16(af[mt], bf[nt], acc[mt][nt], 0, 0, 0);
        }
    }
    float* P = part + (size_t)ks * NROI * NHID;
    int m_base = mb * 128 + wm * 64, n_base = nb * 128 + wn * 64;
#pragma unroll
    for (int mt = 0; mt < 4; ++mt)
#pragma unroll
        for (int nt = 0; nt < 4; ++nt)
#pragma unroll
            for (int i = 0; i < 4; ++i) {
                int m = m_base + mt * 16 + (lane >> 4) * 4 + i;
                int n = n_base + nt * 16 + (lane & 15);
                P[(size_t)m * NHID + n] = acc[mt][nt][i];
            }
}

// ---------------- reduce split-K partials + bias + relu -> hid fp32 ----------------
__global__ __launch_bounds__(256) void reduce_relu(const float* __restrict__ part,
                                                   const float* __restrict__ b1,
                                                   float* __restrict__ hid) {
    int idx = blockIdx.x * 256 + threadIdx.x;   // < 1048576
    float s = b1[idx & (NHID - 1)];
#pragma unroll
    for (int j = 0; j < KSPLIT; ++j) s += part[(size_t)j * NROI * NHID + idx];
    hid[idx] = fmaxf(s, 0.f);
}

// ---------------- GEMM2 + sigmoid -> mask[1024][49] ----------------
__global__ __launch_bounds__(64) void gemm2_mask(const float* __restrict__ hid,
                                                 const float* __restrict__ w2,
                                                 const float* __restrict__ b2,
                                                 float* __restrict__ mask) {
    __shared__ float hrow[NHID];
    int i = blockIdx.x;
    for (int k = threadIdx.x; k < NHID; k += 64) hrow[k] = hid[(size_t)i * NHID + k];
    __syncthreads();
    int j = threadIdx.x;
    if (j < 49) {
        float acc = b2[j];
        for (int k = 0; k < NHID; ++k) acc += hrow[k] * w2[(size_t)k * 49 + j];
        mask[i * 49 + j] = 1.f / (1.f + expf(-acc));
    }
}

// ---------------- out = x * mask (in place on d_out) ----------------
__global__ __launch_bounds__(256) void apply_mask(float* __restrict__ out,
                                                  const float* __restrict__ mask) {
    int idx = blockIdx.x * 256 + threadIdx.x;   // < 12845056
    int i = idx / KDIM;
    int r = idx - i * KDIM;
    int p = r % 49;
    out[idx] = out[idx] * mask[i * 49 + p];
}

extern "C" void kernel_launch(void* const* d_in, const int* in_sizes, int n_in,
                              void* d_out, int out_size, void* d_ws, size_t ws_size,
                              hipStream_t stream) {
    const float* features = (const float*)d_in[0];
    const float* rois     = (const float*)d_in[1];
    const float* w1       = (const float*)d_in[2];
    const float* b1       = (const float*)d_in[3];
    const float* w2       = (const float*)d_in[4];
    const float* b2       = (const float*)d_in[5];
    float* out = (float*)d_out;
    char* ws = (char*)d_ws;

    // ws layout (bytes), total ~156.4 MB
    __hip_bfloat16* featT = (__hip_bfloat16*)(ws);                      // 67,108,864
    __hip_bfloat16* flat  = (__hip_bfloat16*)(ws + 67108864);           // 25,690,112
    __hip_bfloat16* w1t   = (__hip_bfloat16*)(ws + 92798976);           // 25,690,112
    float* part           = (float*)(ws + 118489088);                   // 33,554,432
    float* hid            = (float*)(ws + 152043520);                   // 4,194,304
    float* mask           = (float*)(ws + 156237824);                   // 200,704

    transpose_feat<<<dim3(2048, 8, 2), 256, 0, stream>>>(features, featT);
    transpose_w1<<<dim3(392, 32), 256, 0, stream>>>(w1, w1t);
    roi_align<<<NROI, 256, 0, stream>>>(featT, rois, out, flat);
    gemm1<<<dim3(8, 8, KSPLIT), 256, 0, stream>>>((const u16*)flat, (const u16*)w1t, part);
    reduce_relu<<<4096, 256, 0, stream>>>(part, b1, hid);
    gemm2_mask<<<NROI, 64, 0, stream>>>(hid, w2, b2, mask);
    apply_mask<<<50176, 256, 0, stream>>>(out, mask);
}

// Round 2
// 417.766 us; speedup vs baseline: 1.0702x; 1.0702x over previous
//
#include <hip/hip_runtime.h>
#include <hip/hip_bf16.h>

typedef unsigned short u16;
typedef short short8 __attribute__((ext_vector_type(8)));
typedef float f32x4 __attribute__((ext_vector_type(4)));

#define OUTD 7
#define NROI 1024
#define CH 256
#define KDIM 12544   // 256*49
#define NHID 1024
#define KSPLIT 8

__device__ __forceinline__ float bf2f(u16 u) {
    union { unsigned int i; float f; } v; v.i = ((unsigned int)u) << 16; return v.f;
}
__device__ __forceinline__ u16 f2b(float f) {
    return (u16)(__bfloat16_as_ushort(__float2bfloat16(f)));
}

// ---------------- features (B,C,H,W) fp32 -> featT (B,H,W,C) bf16 ----------------
// tile: 32 ch x 128 px. float4 global loads, uint2 bf16 stores.
__global__ __launch_bounds__(256) void transpose_feat(const float* __restrict__ f,
                                                      u16* __restrict__ ft) {
    __shared__ float tile[32][129];
    int pb = blockIdx.x;          // 0..511 (128 px each)
    int cb = blockIdx.y;          // 0..7
    int b  = blockIdx.z;          // 0..1
    int tid = threadIdx.x;
    const float* src = f + ((size_t)(b * CH + cb * 32)) * 65536 + (size_t)pb * 128;
#pragma unroll
    for (int i = 0; i < 4; ++i) {
        int id = tid + 256 * i;          // 0..1023
        int c = id >> 5, f4 = id & 31;
        float4 v = *(const float4*)(src + (size_t)c * 65536 + f4 * 4);
        tile[c][f4 * 4 + 0] = v.x;
        tile[c][f4 * 4 + 1] = v.y;
        tile[c][f4 * 4 + 2] = v.z;
        tile[c][f4 * 4 + 3] = v.w;
    }
    __syncthreads();
    u16* dst = ft + ((size_t)(b * 65536 + pb * 128)) * CH + cb * 32;
#pragma unroll
    for (int i = 0; i < 4; ++i) {
        int id = tid + 256 * i;
        int px = id >> 3, cg = id & 7;
        uint2 o;
        o.x = (unsigned)f2b(tile[cg * 4 + 0][px]) | ((unsigned)f2b(tile[cg * 4 + 1][px]) << 16);
        o.y = (unsigned)f2b(tile[cg * 4 + 2][px]) | ((unsigned)f2b(tile[cg * 4 + 3][px]) << 16);
        *(uint2*)(dst + (size_t)px * CH + cg * 4) = o;
    }
}

// ---------------- w1 (K,N) fp32 -> w1t (N,K) bf16 ----------------
// tile: 128 k x 32 n, stored transposed in LDS at load time.
__global__ __launch_bounds__(256) void transpose_w1(const float* __restrict__ w1,
                                                    u16* __restrict__ w1t) {
    __shared__ float tile[32][129];   // [n][k]
    int kb = blockIdx.x;              // 0..97
    int nb = blockIdx.y;              // 0..31
    int tid = threadIdx.x;
#pragma unroll
    for (int i = 0; i < 4; ++i) {
        int id = tid + 256 * i;       // 0..1023
        int r = id >> 3, f4 = id & 7; // k-row, n-group
        float4 v = *(const float4*)(w1 + (size_t)(kb * 128 + r) * NHID + nb * 32 + f4 * 4);
        tile[f4 * 4 + 0][r] = v.x;
        tile[f4 * 4 + 1][r] = v.y;
        tile[f4 * 4 + 2][r] = v.z;
        tile[f4 * 4 + 3][r] = v.w;
    }
    __syncthreads();
#pragma unroll
    for (int i = 0; i < 4; ++i) {
        int id = tid + 256 * i;
        int nn = id >> 5, kg = id & 31;
        uint2 o;
        o.x = (unsigned)f2b(tile[nn][kg * 4 + 0]) | ((unsigned)f2b(tile[nn][kg * 4 + 1]) << 16);
        o.y = (unsigned)f2b(tile[nn][kg * 4 + 2]) | ((unsigned)f2b(tile[nn][kg * 4 + 3]) << 16);
        *(uint2*)(w1t + (size_t)(nb * 32 + nn) * KDIM + kb * 128 + kg * 4) = o;
    }
}

// ---------------- rotated RoI align: featT -> x (fp32, into d_out) + flat (bf16) ----------------
// block = 1 roi, 4 waves; wave handles 13/12 whole bins; lane holds 4 channels (uint2 loads).
__global__ __launch_bounds__(256) void roi_align(const u16* __restrict__ ft,
                                                 const float* __restrict__ rois,
                                                 float* __restrict__ x,
                                                 u16* __restrict__ flat) {
    __shared__ float sbuf[49 * 257];   // [bin][c] padded, 50372 B
    int i = blockIdx.x;
    int tid = threadIdx.x;
    int lane = tid & 63, w = tid >> 6;
    float r0 = rois[i * 6 + 0], r1 = rois[i * 6 + 1], r2 = rois[i * 6 + 2];
    float r3 = rois[i * 6 + 3], r4 = rois[i * 6 + 4], th = rois[i * 6 + 5];
    int b = (int)r0;
    float cx = r1 * 0.125f, cy = r2 * 0.125f;
    float rw = fmaxf(r3 * 0.125f, 1.0f), rh = fmaxf(r4 * 0.125f, 1.0f);
    float bw = rw * (1.0f / 7.0f), bh = rh * (1.0f / 7.0f);
    float ct = cosf(th), st = sinf(th);
    const u16* fb = ft + (size_t)b * 65536 * CH;
    int coff = lane * 4;               // this lane's channel group

    int start = w * 12 + (w > 0 ? 1 : 0);
    int cnt = (w == 0) ? 13 : 12;
    for (int bi = 0; bi < cnt; ++bi) {
        int bin = start + bi;
        int ph = bin / 7, pw = bin - ph * 7;
        float a0 = 0.f, a1 = 0.f, a2 = 0.f, a3 = 0.f;
#pragma unroll
        for (int s = 0; s < 4; ++s) {
            int sy = s >> 1, sx2 = s & 1;
            float yy = -rh * 0.5f + ((float)ph + ((float)sy + 0.5f) * 0.5f) * bh;
            float xx = -rw * 0.5f + ((float)pw + ((float)sx2 + 0.5f) * 0.5f) * bw;
            float xs = xx * ct - yy * st + cx;
            float ys = xx * st + yy * ct + cy;
            bool valid = (ys > -1.0f) && (ys < 256.0f) && (xs > -1.0f) && (xs < 256.0f);
            float ysc = fminf(fmaxf(ys, 0.f), 255.f);
            float xsc = fminf(fmaxf(xs, 0.f), 255.f);
            int yl = (int)floorf(ysc), xl = (int)floorf(xsc);
            int yh = min(yl + 1, 255), xh = min(xl + 1, 255);
            float ly = ysc - (float)yl, lx = xsc - (float)xl;
            float hy = 1.f - ly, hx = 1.f - lx;
            float w11 = hy * hx, w12 = hy * lx, w21 = ly * hx, w22 = ly * lx;
            if (!valid) { w11 = w12 = w21 = w22 = 0.f; }
            uint2 v11 = *(const uint2*)(fb + (((size_t)yl * 256 + xl) << 8) + coff);
            uint2 v12 = *(const uint2*)(fb + (((size_t)yl * 256 + xh) << 8) + coff);
            uint2 v21 = *(const uint2*)(fb + (((size_t)yh * 256 + xl) << 8) + coff);
            uint2 v22 = *(const uint2*)(fb + (((size_t)yh * 256 + xh) << 8) + coff);
            a0 += w11 * bf2f(v11.x & 0xffff) + w12 * bf2f(v12.x & 0xffff)
                + w21 * bf2f(v21.x & 0xffff) + w22 * bf2f(v22.x & 0xffff);
            a1 += w11 * bf2f(v11.x >> 16)    + w12 * bf2f(v12.x >> 16)
                + w21 * bf2f(v21.x >> 16)    + w22 * bf2f(v22.x >> 16);
            a2 += w11 * bf2f(v11.y & 0xffff) + w12 * bf2f(v12.y & 0xffff)
                + w21 * bf2f(v21.y & 0xffff) + w22 * bf2f(v22.y & 0xffff);
            a3 += w11 * bf2f(v11.y >> 16)    + w12 * bf2f(v12.y >> 16)
                + w21 * bf2f(v21.y >> 16)    + w22 * bf2f(v22.y >> 16);
        }
        float* sb = sbuf + bin * 257 + coff;
        sb[0] = a0 * 0.25f; sb[1] = a1 * 0.25f; sb[2] = a2 * 0.25f; sb[3] = a3 * 0.25f;
    }
    __syncthreads();
    size_t base = (size_t)i * KDIM;
#pragma unroll 1
    for (int k = 0; k < 49; ++k) {
        int o = tid + k * 256;
        int c = o / 49, bin = o - c * 49;
        float v = sbuf[bin * 257 + c];
        x[base + o] = v;
        flat[base + o] = f2b(v);
    }
}

// ---------------- GEMM1: flat[1024,12544]bf16 @ w1t[1024,12544]^T -> part[ks][1024][1024] fp32 ----------------
__global__ __launch_bounds__(256) void gemm1(const u16* __restrict__ A,
                                             const u16* __restrict__ Bt,
                                             float* __restrict__ part) {
    const int K = KDIM;
    int nb = blockIdx.x, mb = blockIdx.y, ks = blockIdx.z;
    int steps = 24 + (ks < 4 ? 1 : 0);
    int kbase = (ks * 24 + (ks < 4 ? ks : 4)) * 64;
    __shared__ u16 As[128 * 64];
    __shared__ u16 Bs[128 * 64];
    int tid = threadIdx.x;
    int lane = tid & 63, w = tid >> 6;
    int wm = w >> 1, wn = w & 1;
    f32x4 acc[4][4] = {};
    const u16* Ab = A + (size_t)(mb * 128) * K;
    const u16* Bb = Bt + (size_t)(nb * 128) * K;

    for (int s = 0; s < steps; ++s) {
        int kk = kbase + s * 64;
        __syncthreads();
#pragma unroll
        for (int j = 0; j < 4; ++j) {
            int cid = tid + 256 * j;
            int row = cid >> 3, pq = cid & 7;
            int q = pq ^ (row & 7);
            uint4 va = *(const uint4*)(Ab + (size_t)row * K + kk + q * 8);
            *(uint4*)(As + row * 64 + pq * 8) = va;
            uint4 vb = *(const uint4*)(Bb + (size_t)row * K + kk + q * 8);
            *(uint4*)(Bs + row * 64 + pq * 8) = vb;
        }
        __syncthreads();
#pragma unroll
        for (int kh = 0; kh < 2; ++kh) {
            short8 af[4], bf[4];
#pragma unroll
            for (int t = 0; t < 4; ++t) {
                int q = kh * 4 + (lane >> 4);
                int r = wm * 64 + t * 16 + (lane & 15);
                int pq = q ^ (r & 7);
                af[t] = *(const short8*)(As + r * 64 + pq * 8);
                int rb = wn * 64 + t * 16 + (lane & 15);
                int pqb = q ^ (rb & 7);
                bf[t] = *(const short8*)(Bs + rb * 64 + pqb * 8);
            }
#pragma unroll
            for (int mt = 0; mt < 4; ++mt)
#pragma unroll
                for (int nt = 0; nt < 4; ++nt)
                    acc[mt][nt] = __builtin_amdgcn_mfma_f32_16x16x32_bf16(af[mt], bf[nt], acc[mt][nt], 0, 0, 0);
        }
    }
    float* P = part + (size_t)ks * NROI * NHID;
    int m_base = mb * 128 + wm * 64, n_base = nb * 128 + wn * 64;
#pragma unroll
    for (int mt = 0; mt < 4; ++mt)
#pragma unroll
        for (int nt = 0; nt < 4; ++nt)
#pragma unroll
            for (int i = 0; i < 4; ++i) {
                int m = m_base + mt * 16 + (lane >> 4) * 4 + i;
                int n = n_base + nt * 16 + (lane & 15);
                P[(size_t)m * NHID + n] = acc[mt][nt][i];
            }
}

// ---------------- reduce split-K partials + bias + relu -> hid fp32 ----------------
__global__ __launch_bounds__(256) void reduce_relu(const float* __restrict__ part,
                                                   const float* __restrict__ b1,
                                                   float* __restrict__ hid) {
    int idx4 = blockIdx.x * 256 + threadIdx.x;   // < 262144 float4s
    const float4* pv = (const float4*)part;
    const float4* bv = (const float4*)b1;
    float4 s = bv[idx4 & 255];
#pragma unroll
    for (int j = 0; j < KSPLIT; ++j) {
        float4 p = pv[(size_t)j * 262144 + idx4];
        s.x += p.x; s.y += p.y; s.z += p.z; s.w += p.w;
    }
    float4 r;
    r.x = fmaxf(s.x, 0.f); r.y = fmaxf(s.y, 0.f);
    r.z = fmaxf(s.z, 0.f); r.w = fmaxf(s.w, 0.f);
    ((float4*)hid)[idx4] = r;
}

// ---------------- GEMM2 + sigmoid -> mask[1024][49] ----------------
__global__ __launch_bounds__(64) void gemm2_mask(const float* __restrict__ hid,
                                                 const float* __restrict__ w2,
                                                 const float* __restrict__ b2,
                                                 float* __restrict__ mask) {
    __shared__ float hrow[NHID];
    int i = blockIdx.x;
    for (int k = threadIdx.x; k < NHID; k += 64) hrow[k] = hid[(size_t)i * NHID + k];
    __syncthreads();
    int j = threadIdx.x;
    if (j < 49) {
        float acc = b2[j];
        for (int k = 0; k < NHID; ++k) acc += hrow[k] * w2[(size_t)k * 49 + j];
        mask[i * 49 + j] = 1.f / (1.f + expf(-acc));
    }
}

// ---------------- out = x * mask (in place on d_out) ----------------
__global__ __launch_bounds__(256) void apply_mask(float* __restrict__ out,
                                                  const float* __restrict__ mask) {
    __shared__ float mrow[49];
    int i = blockIdx.x;
    int tid = threadIdx.x;
    if (tid < 49) mrow[tid] = mask[i * 49 + tid];
    __syncthreads();
    float4* o = (float4*)(out + (size_t)i * KDIM);
#pragma unroll 1
    for (int idx = tid; idx < 3136; idx += 256) {
        float4 v = o[idx];
        int e = idx * 4;
        int p = e % 49;
        v.x *= mrow[p]; if (++p == 49) p = 0;
        v.y *= mrow[p]; if (++p == 49) p = 0;
        v.z *= mrow[p]; if (++p == 49) p = 0;
        v.w *= mrow[p];
        o[idx] = v;
    }
}

extern "C" void kernel_launch(void* const* d_in, const int* in_sizes, int n_in,
                              void* d_out, int out_size, void* d_ws, size_t ws_size,
                              hipStream_t stream) {
    const float* features = (const float*)d_in[0];
    const float* rois     = (const float*)d_in[1];
    const float* w1       = (const float*)d_in[2];
    const float* b1       = (const float*)d_in[3];
    const float* w2       = (const float*)d_in[4];
    const float* b2       = (const float*)d_in[5];
    float* out = (float*)d_out;
    char* ws = (char*)d_ws;

    u16* featT  = (u16*)(ws);                      // 67,108,864
    u16* flat   = (u16*)(ws + 67108864);           // 25,690,112
    u16* w1t    = (u16*)(ws + 92798976);           // 25,690,112
    float* part = (float*)(ws + 118489088);        // 33,554,432
    float* hid  = (float*)(ws + 152043520);        // 4,194,304
    float* mask = (float*)(ws + 156237824);        // 200,704

    transpose_feat<<<dim3(512, 8, 2), 256, 0, stream>>>(features, featT);
    transpose_w1<<<dim3(98, 32), 256, 0, stream>>>(w1, w1t);
    roi_align<<<NROI, 256, 0, stream>>>(featT, rois, out, flat);
    gemm1<<<dim3(8, 8, KSPLIT), 256, 0, stream>>>(flat, w1t, part);
    reduce_relu<<<1024, 256, 0, stream>>>(part, b1, hid);
    gemm2_mask<<<NROI, 64, 0, stream>>>(hid, w2, b2, mask);
    apply_mask<<<NROI, 256, 0, stream>>>(out, mask);
}

// Round 3
// 386.732 us; speedup vs baseline: 1.1561x; 1.0802x over previous
//
#include <hip/hip_runtime.h>
#include <hip/hip_bf16.h>

typedef unsigned short u16;
typedef unsigned int u32;
typedef short short8 __attribute__((ext_vector_type(8)));
typedef float f32x4 __attribute__((ext_vector_type(4)));

#define OUTD 7
#define NROI 1024
#define CH 256
#define KDIM 12544   // 256*49
#define NHID 1024
#define KSPLIT 8

__device__ __forceinline__ float bf_lo(u32 u) {
    union { u32 i; float f; } v; v.i = u << 16; return v.f;
}
__device__ __forceinline__ float bf_hi(u32 u) {
    union { u32 i; float f; } v; v.i = u & 0xffff0000u; return v.f;
}
__device__ __forceinline__ u16 f2b(float f) {
    return (u16)(__bfloat16_as_ushort(__float2bfloat16(f)));
}
__device__ __forceinline__ void async16(const void* g, void* l) {
    __builtin_amdgcn_global_load_lds((const __attribute__((address_space(1))) u32*)g,
                                     (__attribute__((address_space(3))) u32*)l, 16, 0, 0);
}

// ---------------- features (B,C,H,W) fp32 -> featT (B,H,W,C) bf16 ----------------
__global__ __launch_bounds__(256) void transpose_feat(const float* __restrict__ f,
                                                      u16* __restrict__ ft) {
    __shared__ float tile[32][129];
    int pb = blockIdx.x;          // 0..511 (128 px each)
    int cb = blockIdx.y;          // 0..7
    int b  = blockIdx.z;          // 0..1
    int tid = threadIdx.x;
    const float* src = f + ((size_t)(b * CH + cb * 32)) * 65536 + (size_t)pb * 128;
#pragma unroll
    for (int i = 0; i < 4; ++i) {
        int id = tid + 256 * i;          // 0..1023
        int c = id >> 5, f4 = id & 31;
        float4 v = *(const float4*)(src + (size_t)c * 65536 + f4 * 4);
        tile[c][f4 * 4 + 0] = v.x;
        tile[c][f4 * 4 + 1] = v.y;
        tile[c][f4 * 4 + 2] = v.z;
        tile[c][f4 * 4 + 3] = v.w;
    }
    __syncthreads();
    u16* dst = ft + ((size_t)(b * 65536 + pb * 128)) * CH + cb * 32;
#pragma unroll
    for (int i = 0; i < 4; ++i) {
        int id = tid + 256 * i;
        int px = id >> 3, cg = id & 7;
        uint2 o;
        o.x = (u32)f2b(tile[cg * 4 + 0][px]) | ((u32)f2b(tile[cg * 4 + 1][px]) << 16);
        o.y = (u32)f2b(tile[cg * 4 + 2][px]) | ((u32)f2b(tile[cg * 4 + 3][px]) << 16);
        *(uint2*)(dst + (size_t)px * CH + cg * 4) = o;
    }
}

// ---------------- w1 (K,N) fp32 -> w1t (N,K) bf16 ----------------
__global__ __launch_bounds__(256) void transpose_w1(const float* __restrict__ w1,
                                                    u16* __restrict__ w1t) {
    __shared__ float tile[32][129];   // [n][k]
    int kb = blockIdx.x;              // 0..97
    int nb = blockIdx.y;              // 0..31
    int tid = threadIdx.x;
#pragma unroll
    for (int i = 0; i < 4; ++i) {
        int id = tid + 256 * i;
        int r = id >> 3, f4 = id & 7;
        float4 v = *(const float4*)(w1 + (size_t)(kb * 128 + r) * NHID + nb * 32 + f4 * 4);
        tile[f4 * 4 + 0][r] = v.x;
        tile[f4 * 4 + 1][r] = v.y;
        tile[f4 * 4 + 2][r] = v.z;
        tile[f4 * 4 + 3][r] = v.w;
    }
    __syncthreads();
#pragma unroll
    for (int i = 0; i < 4; ++i) {
        int id = tid + 256 * i;
        int nn = id >> 5, kg = id & 31;
        uint2 o;
        o.x = (u32)f2b(tile[nn][kg * 4 + 0]) | ((u32)f2b(tile[nn][kg * 4 + 1]) << 16);
        o.y = (u32)f2b(tile[nn][kg * 4 + 2]) | ((u32)f2b(tile[nn][kg * 4 + 3]) << 16);
        *(uint2*)(w1t + (size_t)(nb * 32 + nn) * KDIM + kb * 128 + kg * 4) = o;
    }
}

// ---------------- w2 (K,49) fp32 -> w2t (49,K) ----------------
__global__ __launch_bounds__(256) void transpose_w2(const float* __restrict__ w2,
                                                    float* __restrict__ w2t) {
    int j = blockIdx.x;   // 0..48
    for (int k = threadIdx.x; k < NHID; k += 256)
        w2t[(size_t)j * NHID + k] = w2[(size_t)k * 49 + j];
}

// ---------------- rotated RoI align: featT -> flat (bf16) ----------------
__global__ __launch_bounds__(256) void roi_align(const u16* __restrict__ ft,
                                                 const float* __restrict__ rois,
                                                 u16* __restrict__ flat) {
    __shared__ u16 sbuf[49 * 260];   // [bin][c], pad 260 keeps uint2 alignment; 25480 B
    int i = blockIdx.x;
    int tid = threadIdx.x;
    int lane = tid & 63, w = tid >> 6;
    float r0 = rois[i * 6 + 0], r1 = rois[i * 6 + 1], r2 = rois[i * 6 + 2];
    float r3 = rois[i * 6 + 3], r4 = rois[i * 6 + 4], th = rois[i * 6 + 5];
    int b = (int)r0;
    float cx = r1 * 0.125f, cy = r2 * 0.125f;
    float rw = fmaxf(r3 * 0.125f, 1.0f), rh = fmaxf(r4 * 0.125f, 1.0f);
    float bw = rw * (1.0f / 7.0f), bh = rh * (1.0f / 7.0f);
    float ct = cosf(th), st = sinf(th);
    const u16* fb = ft + (size_t)b * 65536 * CH;
    int coff = lane * 4;

    int start = w * 12 + (w > 0 ? 1 : 0);
    int cnt = (w == 0) ? 13 : 12;
    for (int bi = 0; bi < cnt; ++bi) {
        int bin = start + bi;
        int ph = bin / 7, pw = bin - ph * 7;
        float a0 = 0.f, a1 = 0.f, a2 = 0.f, a3 = 0.f;
#pragma unroll
        for (int s = 0; s < 4; ++s) {
            int sy = s >> 1, sx2 = s & 1;
            float yy = -rh * 0.5f + ((float)ph + ((float)sy + 0.5f) * 0.5f) * bh;
            float xx = -rw * 0.5f + ((float)pw + ((float)sx2 + 0.5f) * 0.5f) * bw;
            float xs = xx * ct - yy * st + cx;
            float ys = xx * st + yy * ct + cy;
            bool valid = (ys > -1.0f) && (ys < 256.0f) && (xs > -1.0f) && (xs < 256.0f);
            float ysc = fminf(fmaxf(ys, 0.f), 255.f);
            float xsc = fminf(fmaxf(xs, 0.f), 255.f);
            int yl = (int)floorf(ysc), xl = (int)floorf(xsc);
            int yh = min(yl + 1, 255), xh = min(xl + 1, 255);
            float ly = ysc - (float)yl, lx = xsc - (float)xl;
            float hy = 1.f - ly, hx = 1.f - lx;
            float w11 = hy * hx, w12 = hy * lx, w21 = ly * hx, w22 = ly * lx;
            if (!valid) { w11 = w12 = w21 = w22 = 0.f; }
            uint2 v11 = *(const uint2*)(fb + (((size_t)yl * 256 + xl) << 8) + coff);
            uint2 v12 = *(const uint2*)(fb + (((size_t)yl * 256 + xh) << 8) + coff);
            uint2 v21 = *(const uint2*)(fb + (((size_t)yh * 256 + xl) << 8) + coff);
            uint2 v22 = *(const uint2*)(fb + (((size_t)yh * 256 + xh) << 8) + coff);
            a0 += w11 * bf_lo(v11.x) + w12 * bf_lo(v12.x) + w21 * bf_lo(v21.x) + w22 * bf_lo(v22.x);
            a1 += w11 * bf_hi(v11.x) + w12 * bf_hi(v12.x) + w21 * bf_hi(v21.x) + w22 * bf_hi(v22.x);
            a2 += w11 * bf_lo(v11.y) + w12 * bf_lo(v12.y) + w21 * bf_lo(v21.y) + w22 * bf_lo(v22.y);
            a3 += w11 * bf_hi(v11.y) + w12 * bf_hi(v12.y) + w21 * bf_hi(v21.y) + w22 * bf_hi(v22.y);
        }
        uint2 o;
        o.x = (u32)f2b(a0 * 0.25f) | ((u32)f2b(a1 * 0.25f) << 16);
        o.y = (u32)f2b(a2 * 0.25f) | ((u32)f2b(a3 * 0.25f) << 16);
        *(uint2*)(sbuf + bin * 260 + coff) = o;
    }
    __syncthreads();
    // write flat[i][c*49+bin], 4 elems/thread/iter, coalesced uint2 stores
    uint2* fl = (uint2*)(flat + (size_t)i * KDIM);
#pragma unroll 1
    for (int k = tid; k < 3136; k += 256) {
        int e = k * 4;
        int c = e / 49, bn = e - c * 49;
        u16 r0_ = sbuf[bn * 260 + c]; if (++bn == 49) { bn = 0; ++c; }
        u16 r1_ = sbuf[bn * 260 + c]; if (++bn == 49) { bn = 0; ++c; }
        u16 r2_ = sbuf[bn * 260 + c]; if (++bn == 49) { bn = 0; ++c; }
        u16 r3_ = sbuf[bn * 260 + c];
        uint2 o;
        o.x = (u32)r0_ | ((u32)r1_ << 16);
        o.y = (u32)r2_ | ((u32)r3_ << 16);
        fl[k] = o;
    }
}

// ---------------- GEMM1: flat[1024,12544]bf16 @ w1t[1024,12544]^T -> part fp32 ----------------
// 128x128 tile, BK=64, global_load_lds width=16, XOR-8 swizzle applied on the GLOBAL side.
__global__ __launch_bounds__(256) void gemm1(const u16* __restrict__ A,
                                             const u16* __restrict__ Bt,
                                             float* __restrict__ part) {
    const int K = KDIM;
    int nb = blockIdx.x, mb = blockIdx.y, ks = blockIdx.z;
    int steps = 24 + (ks < 4 ? 1 : 0);
    int kbase = (ks * 24 + (ks < 4 ? ks : 4)) * 64;
    __shared__ u16 As[128 * 64];
    __shared__ u16 Bs[128 * 64];
    int tid = threadIdx.x;
    int lane = tid & 63, w = tid >> 6;
    int wm = w >> 1, wn = w & 1;
    f32x4 acc[4][4] = {};
    const u16* Ab = A + (size_t)(mb * 128) * K;
    const u16* Bb = Bt + (size_t)(nb * 128) * K;

    for (int s = 0; s < steps; ++s) {
        int kk = kbase + s * 64;
        __syncthreads();
        // stage: 16 wave-chunks of 1KB each for A and B; lane L of chunk c lands at
        // LDS c*512 + L*8 (u16) == row*64 + pq*8 with row=c*8+(L>>3), pq=L&7.
#pragma unroll
        for (int j = 0; j < 4; ++j) {
            int c = w * 4 + j;                 // 0..15
            int cid = c * 64 + lane;           // 0..1023
            int row = cid >> 3, pq = cid & 7;
            int q = pq ^ (row & 7);            // global-side swizzle
            async16(Ab + (size_t)row * K + kk + q * 8, As + c * 512 + lane * 8);
            async16(Bb + (size_t)row * K + kk + q * 8, Bs + c * 512 + lane * 8);
        }
        __syncthreads();
#pragma unroll
        for (int kh = 0; kh < 2; ++kh) {
            short8 af[4], bf[4];
#pragma unroll
            for (int t = 0; t < 4; ++t) {
                int q = kh * 4 + (lane >> 4);
                int r = wm * 64 + t * 16 + (lane & 15);
                int pq = q ^ (r & 7);
                af[t] = *(const short8*)(As + r * 64 + pq * 8);
                int rb = wn * 64 + t * 16 + (lane & 15);
                int pqb = q ^ (rb & 7);
                bf[t] = *(const short8*)(Bs + rb * 64 + pqb * 8);
            }
#pragma unroll
            for (int mt = 0; mt < 4; ++mt)
#pragma unroll
                for (int nt = 0; nt < 4; ++nt)
                    acc[mt][nt] = __builtin_amdgcn_mfma_f32_16x16x32_bf16(af[mt], bf[nt], acc[mt][nt], 0, 0, 0);
        }
    }
    float* P = part + (size_t)ks * NROI * NHID;
    int m_base = mb * 128 + wm * 64, n_base = nb * 128 + wn * 64;
#pragma unroll
    for (int mt = 0; mt < 4; ++mt)
#pragma unroll
        for (int nt = 0; nt < 4; ++nt)
#pragma unroll
            for (int i = 0; i < 4; ++i) {
                int m = m_base + mt * 16 + (lane >> 4) * 4 + i;
                int n = n_base + nt * 16 + (lane & 15);
                P[(size_t)m * NHID + n] = acc[mt][nt][i];
            }
}

// ---------------- reduce split-K partials + bias + relu -> hid fp32 ----------------
__global__ __launch_bounds__(256) void reduce_relu(const float* __restrict__ part,
                                                   const float* __restrict__ b1,
                                                   float* __restrict__ hid) {
    int idx4 = blockIdx.x * 256 + threadIdx.x;   // < 262144 float4s
    const float4* pv = (const float4*)part;
    const float4* bv = (const float4*)b1;
    float4 s = bv[idx4 & 255];
#pragma unroll
    for (int j = 0; j < KSPLIT; ++j) {
        float4 p = pv[(size_t)j * 262144 + idx4];
        s.x += p.x; s.y += p.y; s.z += p.z; s.w += p.w;
    }
    float4 r;
    r.x = fmaxf(s.x, 0.f); r.y = fmaxf(s.y, 0.f);
    r.z = fmaxf(s.z, 0.f); r.w = fmaxf(s.w, 0.f);
    ((float4*)hid)[idx4] = r;
}

// ---------------- GEMM2 + sigmoid + apply: out = bf2f(flat) * mask ----------------
__global__ __launch_bounds__(256) void gemm2_apply(const float* __restrict__ hid,
                                                   const float* __restrict__ w2t,
                                                   const float* __restrict__ b2,
                                                   const u16* __restrict__ flat,
                                                   float* __restrict__ out) {
    __shared__ __align__(16) float hrow[NHID];
    __shared__ float partial[256];
    __shared__ float mrow[49];
    int i = blockIdx.x;
    int tid = threadIdx.x;
    for (int k = tid; k < NHID; k += 256) hrow[k] = hid[(size_t)i * NHID + k];
    __syncthreads();
    float p = 0.f;
    if (tid < 245) {
        int j = tid / 5, kc = tid - (tid / 5) * 5;
        int k0 = (256 * kc) / 5, k1 = (256 * (kc + 1)) / 5;   // float4 chunks
        const float4* wv = (const float4*)(w2t + (size_t)j * NHID);
        const float4* hv = (const float4*)hrow;
        for (int k = k0; k < k1; ++k) {
            float4 a = hv[k], b = wv[k];
            p += a.x * b.x + a.y * b.y + a.z * b.z + a.w * b.w;
        }
    }
    partial[tid] = p;
    __syncthreads();
    if (tid < 49) {
        float s = b2[tid];
#pragma unroll
        for (int q = 0; q < 5; ++q) s += partial[tid * 5 + q];
        mrow[tid] = 1.f / (1.f + expf(-s));
    }
    __syncthreads();
    const uint2* fl = (const uint2*)(flat + (size_t)i * KDIM);
    float4* op = (float4*)(out + (size_t)i * KDIM);
#pragma unroll 1
    for (int idx = tid; idx < 3136; idx += 256) {
        uint2 v = fl[idx];
        int e = idx * 4;
        int pp = e - (e / 49) * 49;
        float4 r;
        r.x = bf_lo(v.x) * mrow[pp]; if (++pp == 49) pp = 0;
        r.y = bf_hi(v.x) * mrow[pp]; if (++pp == 49) pp = 0;
        r.z = bf_lo(v.y) * mrow[pp]; if (++pp == 49) pp = 0;
        r.w = bf_hi(v.y) * mrow[pp];
        op[idx] = r;
    }
}

extern "C" void kernel_launch(void* const* d_in, const int* in_sizes, int n_in,
                              void* d_out, int out_size, void* d_ws, size_t ws_size,
                              hipStream_t stream) {
    const float* features = (const float*)d_in[0];
    const float* rois     = (const float*)d_in[1];
    const float* w1       = (const float*)d_in[2];
    const float* b1       = (const float*)d_in[3];
    const float* w2       = (const float*)d_in[4];
    const float* b2       = (const float*)d_in[5];
    float* out = (float*)d_out;
    char* ws = (char*)d_ws;

    u16* featT  = (u16*)(ws);                      // 67,108,864
    u16* flat   = (u16*)(ws + 67108864);           // 25,690,112
    u16* w1t    = (u16*)(ws + 92798976);           // 25,690,112
    float* part = (float*)(ws + 118489088);        // 33,554,432
    float* hid  = (float*)(ws + 152043520);        // 4,194,304
    float* w2t  = (float*)(ws + 156237824);        // 200,704

    transpose_feat<<<dim3(512, 8, 2), 256, 0, stream>>>(features, featT);
    transpose_w1<<<dim3(98, 32), 256, 0, stream>>>(w1, w1t);
    transpose_w2<<<49, 256, 0, stream>>>(w2, w2t);
    roi_align<<<NROI, 256, 0, stream>>>(featT, rois, flat);
    gemm1<<<dim3(8, 8, KSPLIT), 256, 0, stream>>>(flat, w1t, part);
    reduce_relu<<<1024, 256, 0, stream>>>(part, b1, hid);
    gemm2_apply<<<NROI, 256, 0, stream>>>(hid, w2t, b2, flat, out);
}